// Round 4
// baseline (738.117 us; speedup 1.0000x reference)
//
#include <hip/hip_runtime.h>

// CRF forward v4b: ONE WAVE per sequence, REGISTER-ONLY alpha exchange.
// v1/v3 post-mortem: ~600 cyc/step of the recurrence is the LDS round-trip
// of the alpha vector (write-drain + read latency), present with or without
// barriers. v4b removes LDS from the recurrence entirely: alpha (128 f16 =
// 64 dwords) lives one dword per lane; the matvec's all-to-all is a 64-op
// cross-lane gather done in 4 quadrant chunks of 16 (expand-then-consume,
// to cap register liveness):
//   - v_permlane32_swap  (+-32; semantics validated in v3's half_sum)
//   - ds_swizzle 0x401F  (xor-16; addressless lane permute, no memory)
//   - DPP row_ror doubling (1,2,4,8) within 16-lane rows
// The E matrix is loaded PERMUTED VIA A PROBE: lane-id pushed through the
// *same* base4/expand16 network gives the source lane of every slot, so
// the pairing is correct by construction whatever the hw permutation is.
// Per step: 64 gather ops + 128 fdot2 (8 chains of 16) + v1's validated
// tail (stale power-of-2 normalizer P = Em - P + 6, exact integer Kacc).
// No LDS, no barriers, no waitcnt drains in the loop.

typedef _Float16 half_t;
typedef _Float16 h2 __attribute__((ext_vector_type(2)));

#define TB  1024
#define NUM 126
#define LBL 128

__device__ __forceinline__ float dot2f(h2 a, h2 b, float c) {
  return __builtin_amdgcn_fdot2(a, b, c, false);
}

__device__ __forceinline__ h2 bits_h2(int x) {
  union { int i; h2 h; } u; u.i = x; return u.h;
}
__device__ __forceinline__ int h2_bits(h2 h) {
  union { int i; h2 h; } u; u.h = h; return u.i;
}

template <int N>
__device__ __forceinline__ int ror(int x) {
  return __builtin_amdgcn_update_dpp(x, x, 0x120 | N, 0xF, 0xF, false);
}

template <int CTRL>
__device__ __forceinline__ float dpp_max_step(float x) {
  int xi = __float_as_int(x);
  int yi = __builtin_amdgcn_update_dpp(xi, xi, CTRL, 0xF, 0xF, false);
  return fmaxf(x, __int_as_float(yi));
}

// max over all 64 lanes -> uniform via readlane(63)  (validated in v1)
__device__ __forceinline__ float wave_max64(float x) {
  x = dpp_max_step<0x111>(x);  // row_shr:1
  x = dpp_max_step<0x112>(x);  // row_shr:2
  x = dpp_max_step<0x114>(x);  // row_shr:4
  x = dpp_max_step<0x118>(x);  // row_shr:8
  x = dpp_max_step<0x142>(x);  // row_bcast:15
  x = dpp_max_step<0x143>(x);  // row_bcast:31
  return __int_as_float(__builtin_amdgcn_readlane(__float_as_int(x), 63));
}

// 4 quadrant bases from one dword: {self/±32 halves} x {xor-16}.
__device__ __forceinline__ void base4(int cur, int g[4]) {
  int g0 = cur, g1 = cur;
  asm("v_permlane32_swap_b32 %0, %1" : "+v"(g0), "+v"(g1));
  g[0] = g0;
  g[1] = g1;
  g[2] = __builtin_amdgcn_ds_swizzle(g0, 0x401F);
  g[3] = __builtin_amdgcn_ds_swizzle(g1, 0x401F);
}

// 16 slots from one base via row_ror doubling (depth-4 chain).
__device__ __forceinline__ void expand16(int base, int rr[16]) {
  rr[0]  = base;
  rr[1]  = ror<1>(rr[0]);
  rr[2]  = ror<2>(rr[0]);  rr[3]  = ror<2>(rr[1]);
  rr[4]  = ror<4>(rr[0]);  rr[5]  = ror<4>(rr[1]);
  rr[6]  = ror<4>(rr[2]);  rr[7]  = ror<4>(rr[3]);
  rr[8]  = ror<8>(rr[0]);  rr[9]  = ror<8>(rr[1]);
  rr[10] = ror<8>(rr[2]);  rr[11] = ror<8>(rr[3]);
  rr[12] = ror<8>(rr[4]);  rr[13] = ror<8>(rr[5]);
  rr[14] = ror<8>(rr[6]);  rr[15] = ror<8>(rr[7]);
}

__global__ __launch_bounds__(64, 1)
void crf_fwd(const float* __restrict__ logits, const int* __restrict__ labels,
             const int* __restrict__ lens, const float* __restrict__ trans,
             float* __restrict__ out)
{
  const int b  = blockIdx.x;
  const int l  = threadIdx.x;          // lane 0..63
  const int r0 = 2 * l;                // even state owned by this lane
  const int r1 = 2 * l + 1;            // odd state
  const float rm0 = (r0 < NUM) ? 1.0f : 0.0f;   // states 126,127 dead
  const float rm1 = (r1 < NUM) ? 1.0f : 0.0f;
  const int cl  = (r1 < NUM) ? r0 : (NUM - 2);  // even, float2-safe col base
  const int len = lens[b];

  const float* lgbase = logits + (size_t)b * TB * NUM;
  const int*   lab    = labels + (size_t)b * TB;

  // ---- E rows (f16), permuted via the probe: slot k of quadrant v pairs
  // with the alpha dword of source lane s -> states (2s, 2s+1).
  h2 E0[64], E1[64];
  {
    int g[4];
    base4(l, g);                        // PROBE: lane id through the network
    const float* t0 = trans + r0 * LBL;
    const float* t1 = trans + r1 * LBL;
    #pragma unroll
    for (int v = 0; v < 4; ++v) {
      int rr[16];
      expand16(g[v], rr);
      #pragma unroll
      for (int k = 0; k < 16; ++k) {
        int s = rr[k];                  // source lane of this slot
        h2 e0, e1;
        e0[0] = (half_t)__expf(t0[2 * s]);
        e0[1] = (half_t)__expf(t0[2 * s + 1]);
        e1[0] = (half_t)__expf(t1[2 * s]);
        e1[1] = (half_t)__expf(t1[2 * s + 1]);
        E0[16 * v + k] = e0;
        E1[16 * v + k] = e1;
      }
    }
  }

  // ---- gold score (one-time, off the recurrence)
  float g = 0.f;
  #pragma unroll
  for (int kk = 0; kk < 16; ++kk) {
    int t = l + 64 * kk;
    if (t < len) {
      int lt = lab[t];
      int lp = (t == 0) ? (LBL - 2) : lab[t - 1];   // start state = 126
      g += lgbase[(size_t)t * NUM + lt] + trans[lt * LBL + lp];
    }
  }
  if (l == 0) g += trans[(LBL - 1) * LBL + lab[len - 1]];  // -> end
  #pragma unroll
  for (int o = 1; o < 64; o <<= 1) g += __shfl_xor(g, o);
  const float gold = g;

  // ---- state of the recurrence (all registers)
  h2 a_init;
  a_init[0] = (half_t)((r0 == LBL - 2) ? 1.0f : 0.0f);  // lane 63: (a126,a127)
  a_init[1] = (half_t)0.0f;
  int   cur = h2_bits(a_init);
  int   P = 6, Kacc = 0, Kout = 0;
  float w0_out = 1.f, w1_out = 1.f;

  // ---- logit prefetch: 4 rows deep, one aligned float2 per step
  float2 plg[4];
  #pragma unroll
  for (int d = 0; d < 4; ++d)
    plg[d] = *(const float2*)(lgbase + (size_t)d * NUM + cl);

  // ---- one recurrence step (inlined 7x for the prefetch pipeline)
  auto step = [&](float2 Qv) __attribute__((always_inline)) {
    int gq[4];
    base4(cur, gq);
    float eL0 = __expf(Qv.x) * rm0;
    float eL1 = __expf(Qv.y) * rm1;
    float a0 = 0.f, a1 = 0.f, a2 = 0.f, a3 = 0.f;
    float b0 = 0.f, b1 = 0.f, b2 = 0.f, b3 = 0.f;
    {
      int rr[16];
      expand16(gq[0], rr);
      #pragma unroll
      for (int k = 0; k < 16; ++k) {
        h2 x = bits_h2(rr[k]);
        a0 = dot2f(x, E0[k], a0);  b0 = dot2f(x, E1[k], b0);
      }
    }
    {
      int rr[16];
      expand16(gq[1], rr);
      #pragma unroll
      for (int k = 0; k < 16; ++k) {
        h2 x = bits_h2(rr[k]);
        a1 = dot2f(x, E0[16 + k], a1);  b1 = dot2f(x, E1[16 + k], b1);
      }
    }
    {
      int rr[16];
      expand16(gq[2], rr);
      #pragma unroll
      for (int k = 0; k < 16; ++k) {
        h2 x = bits_h2(rr[k]);
        a2 = dot2f(x, E0[32 + k], a2);  b2 = dot2f(x, E1[32 + k], b2);
      }
    }
    {
      int rr[16];
      expand16(gq[3], rr);
      #pragma unroll
      for (int k = 0; k < 16; ++k) {
        h2 x = bits_h2(rr[k]);
        a3 = dot2f(x, E0[48 + k], a3);  b3 = dot2f(x, E1[48 + k], b3);
      }
    }
    float w0 = ((a0 + a1) + (a2 + a3)) * eL0;
    float w1 = ((b0 + b1) + (b2 + b3)) * eL1;
    float sc = __int_as_float((127 - P) << 23);   // 2^-P, EXACT
    h2 pk;
    pk[0] = (half_t)(w0 * sc);
    pk[1] = (half_t)(w1 * sc);
    cur = h2_bits(pk);                 // next step reads the REGISTER
    Kout = Kacc;  Kacc += P;           // SALU side chain
    float m  = wave_max64(fmaxf(w0, w1));   // off-chain: feeds next step
    int   Em = ((__float_as_int(m) >> 23) & 0xFF) - 127;
    P = Em - P + 6;                    // feedback: bounded, no random walk
    w0_out = w0;  w1_out = w1;
  };

  int t = 0;
  for (; t + 4 <= len; t += 4) {
    int q0 = t + 4, q1 = t + 5, q2 = t + 6, q3 = t + 7;
    q0 = (q0 < TB) ? q0 : (TB - 1);  q1 = (q1 < TB) ? q1 : (TB - 1);
    q2 = (q2 < TB) ? q2 : (TB - 1);  q3 = (q3 < TB) ? q3 : (TB - 1);
    step(plg[0]);
    plg[0] = *(const float2*)(lgbase + (size_t)q0 * NUM + cl);
    step(plg[1]);
    plg[1] = *(const float2*)(lgbase + (size_t)q1 * NUM + cl);
    step(plg[2]);
    plg[2] = *(const float2*)(lgbase + (size_t)q2 * NUM + cl);
    step(plg[3]);
    plg[3] = *(const float2*)(lgbase + (size_t)q3 * NUM + cl);
  }
  const int rem = len - t;
  if (rem > 0) step(plg[0]);
  if (rem > 1) step(plg[1]);
  if (rem > 2) step(plg[2]);

  // ---- alpha_len[j] = Kout*ln2 + log(w_len[j]); norm = logsumexp(+trans_end)
  const float LN2 = 0.6931471805599453f;
  float K = (float)Kout * LN2;
  float v0 = K + __logf(w0_out) + trans[(LBL - 1) * LBL + r0];
  float v1 = K + __logf(w1_out) + trans[(LBL - 1) * LBL + r1];
  float M = wave_max64(fmaxf(v0, v1));
  float p = __expf(v0 - M) + __expf(v1 - M);    // dead states: w=0 -> 0
  #pragma unroll
  for (int o = 1; o < 64; o <<= 1) p += __shfl_xor(p, o);
  if (l == 0) out[b] = gold - (M + __logf(p));
}

extern "C" void kernel_launch(void* const* d_in, const int* in_sizes, int n_in,
                              void* d_out, int out_size, void* d_ws, size_t ws_size,
                              hipStream_t stream) {
  const float* logits = (const float*)d_in[0];
  const int*   labels = (const int*)d_in[1];
  const int*   lens   = (const int*)d_in[2];
  const float* trans  = (const float*)d_in[3];
  float* out = (float*)d_out;
  (void)in_sizes; (void)n_in; (void)out_size; (void)d_ws; (void)ws_size;
  crf_fwd<<<256, 64, 0, stream>>>(logits, labels, lens, trans, out);
}

// Round 5
// 530.614 us; speedup vs baseline: 1.3911x; 1.3911x over previous
//
#include <hip/hip_runtime.h>

// CRF forward v5: 4 waves/seq, R=4 rows x C=16 cols per lane, and the
// normalizer P computed from the READ side.
// Post-mortems: v3 (LDS exchange, w-side max ring) = 808 cyc/step; v4b
// (register exchange) = 1390 (AGPR spill of the 128-reg E + ds_swizzle on
// chain). v5 keeps the minimal-LDS exchange but removes the max ring from
// the chain entirely using the identity  P_t = exponent(max a_{t-1}) + 6
// (bit-identical to v1's validated stale feedback P = Em - P + 6, since
// a = w*2^-P with exact power-of-2 scale). Every wave reads ALL 128 states
// (8-lane broadcast per address), so each wave derives the SAME P locally:
// no maxsh ring, no pre-barrier wave tree, no extra drain.
// Per lane: 2x ds_read_b128 (32 B of a), 32 fdot2 (4 rows x 2 chains of 4),
// reduction over 8 lanes/row = quad_perm xor1 + quad_perm xor2 + row_ror:8
// (= exact xor8 within a 16-lane row) -- all pure VALU, colgroup in lane
// bits {0,1,3}. P-tree (7 v_pk_max_f16 + DPP max tree) runs in the dot
// shadow. Writers (colgroup==0) store 4 states as one b64.
// Sync: one "s_waitcnt lgkmcnt(0); s_barrier" per step, no vmcnt drain
// (4-deep global logit prefetch stays in flight). Kacc integer side chain
// exact. E = 32 VGPRs -> no spills.

typedef _Float16 half_t;
typedef _Float16 h2 __attribute__((ext_vector_type(2)));

#define TB  1024
#define NUM 126
#define LBL 128

__device__ __forceinline__ float dot2f(h2 a, h2 b, float c) {
  return __builtin_amdgcn_fdot2(a, b, c, false);
}

__device__ __forceinline__ h2 bits_h2(unsigned x) {
  union { unsigned i; h2 h; } u; u.i = x; return u.h;
}
__device__ __forceinline__ unsigned h2_bits(h2 h) {
  union { unsigned i; h2 h; } u; u.h = h; return u.i;
}

// packed f16 max (values are >= 0, no NaN) -- VOP3P, 1 instr
__device__ __forceinline__ unsigned pkmax(unsigned a, unsigned b) {
  unsigned r;
  asm("v_pk_max_f16 %0, %1, %2" : "=v"(r) : "v"(a), "v"(b));
  return r;
}

template <int CTRL>
__device__ __forceinline__ float dpp_fadd(float x) {
  int xi = __float_as_int(x);
  int yi = __builtin_amdgcn_update_dpp(xi, xi, CTRL, 0xF, 0xF, false);
  return x + __int_as_float(yi);
}
template <int CTRL>
__device__ __forceinline__ float dpp_fmax(float x) {
  int xi = __float_as_int(x);
  int yi = __builtin_amdgcn_update_dpp(xi, xi, CTRL, 0xF, 0xF, false);
  return fmaxf(x, __int_as_float(yi));
}

// row-sum butterfly over lane bits {0,1,3}: xor1, xor2, xor8-within-16.
// (row_ror:8 within a 16-lane row maps l -> l^8 exactly: +8 mod 16 flips
// bit 3 and leaves bits 0-2 unchanged.)
__device__ __forceinline__ float colsum8(float x) {
  x = dpp_fadd<0xB1>(x);    // quad_perm {1,0,3,2} = xor1
  x = dpp_fadd<0x4E>(x);    // quad_perm {2,3,0,1} = xor2
  x = dpp_fadd<0x128>(x);   // row_ror:8            = xor8
  return x;
}

// max over all 64 lanes -> uniform via readlane(63)  (validated v1/v3)
__device__ __forceinline__ float wave_max64(float x) {
  x = dpp_fmax<0x111>(x);  // row_shr:1
  x = dpp_fmax<0x112>(x);  // row_shr:2
  x = dpp_fmax<0x114>(x);  // row_shr:4
  x = dpp_fmax<0x118>(x);  // row_shr:8
  x = dpp_fmax<0x142>(x);  // row_bcast:15
  x = dpp_fmax<0x143>(x);  // row_bcast:31
  return __int_as_float(__builtin_amdgcn_readlane(__float_as_int(x), 63));
}

__global__ __launch_bounds__(256, 1)
void crf_fwd(const float* __restrict__ logits, const int* __restrict__ labels,
             const int* __restrict__ lens, const float* __restrict__ trans,
             float* __restrict__ out)
{
  const int b   = blockIdx.x;
  const int tid = threadIdx.x;
  const int wid = tid >> 6;                       // wave 0..3
  const int l   = tid & 63;                       // lane 0..63
  const int c   = (l & 3) | ((l & 8) >> 1);       // colgroup 0..7 (bits 0,1,3)
  const int gl  = ((l >> 2) & 1) | ((l >> 3) & 6);// rowgroup lane bits (2,4,5)
  const int g   = (wid << 3) | gl;                // rowgroup 0..31
  const int row0 = g << 2;                        // rows row0..row0+3
  const bool writer = ((l & 11) == 0);            // colgroup == 0
  const float rm0 = (row0 + 0 < NUM) ? 1.0f : 0.0f;
  const float rm1 = (row0 + 1 < NUM) ? 1.0f : 0.0f;
  const float rm2 = (row0 + 2 < NUM) ? 1.0f : 0.0f;
  const float rm3 = (row0 + 3 < NUM) ? 1.0f : 0.0f;
  const int clb = (row0 <= NUM - 4) ? row0 : (NUM - 4);  // float2-safe base
  const bool sh2 = (clb != row0);                 // true only for g=31
  const int len = lens[b];

  __shared__ __align__(16) h2 a_sh[2][64];        // a[parity]; dword s=(a2s,a2s+1)
  __shared__ float goldsh[4], Msh[4], psh[4];

  const float* lgbase = logits + (size_t)b * TB * NUM;
  const int*   lab    = labels + (size_t)b * TB;

  // ---- E = exp(trans) block: rows row0..+3, cols 16c..16c+15 (32 VGPRs)
  h2 E[4][8];
  #pragma unroll
  for (int i = 0; i < 4; ++i) {
    const float* tr = trans + (row0 + i) * LBL + 16 * c;
    #pragma unroll
    for (int j = 0; j < 8; ++j) {
      h2 e;
      e[0] = (half_t)__expf(tr[2 * j]);
      e[1] = (half_t)__expf(tr[2 * j + 1]);
      E[i][j] = e;
    }
  }

  // ---- gold score (one-time, 256 threads)
  float gg = 0.f;
  #pragma unroll
  for (int kk = 0; kk < 4; ++kk) {
    int t = tid + 256 * kk;
    if (t < len) {
      int lt = lab[t];
      int lp = (t == 0) ? (LBL - 2) : lab[t - 1];   // start state = 126
      gg += lgbase[(size_t)t * NUM + lt] + trans[lt * LBL + lp];
    }
  }
  if (tid == 0) gg += trans[(LBL - 1) * LBL + lab[len - 1]];  // -> end
  #pragma unroll
  for (int o = 1; o < 64; o <<= 1) gg += __shfl_xor(gg, o);
  if (l == 0) goldsh[wid] = gg;

  // ---- a_0 = one-hot(start=126)  (max a_0 = 1.0 -> first P = 6, like v1)
  if (tid < 64) {
    h2 ai;
    ai[0] = (half_t)((2 * tid     == LBL - 2) ? 1.0f : 0.0f);
    ai[1] = (half_t)((2 * tid + 1 == LBL - 2) ? 1.0f : 0.0f);
    a_sh[0][tid] = ai;
  }
  __syncthreads();

  // ---- logit prefetch, 4 rows deep: two aligned float2 per step
  float2 pA[4], pB[4];
  #pragma unroll
  for (int d = 0; d < 4; ++d) {
    pA[d] = *(const float2*)(lgbase + (size_t)d * NUM + clb);
    pB[d] = *(const float2*)(lgbase + (size_t)d * NUM + clb + 2);
  }

  int   Kacc = 0, Kout = 0, par = 0;
  float w0_out = 1.f, w1_out = 1.f, w2_out = 1.f, w3_out = 1.f;

  auto step = [&](float2 A, float2 B) __attribute__((always_inline)) {
    // a-read: 16 states = 2 x b128 (8-lane broadcast per address)
    const uint4* ap = (const uint4*)(&a_sh[par][8 * c]);
    uint4 u0 = ap[0], u1 = ap[1];
    h2 d0 = bits_h2(u0.x), d1 = bits_h2(u0.y), d2 = bits_h2(u0.z), d3 = bits_h2(u0.w);
    h2 d4 = bits_h2(u1.x), d5 = bits_h2(u1.y), d6 = bits_h2(u1.z), d7 = bits_h2(u1.w);
    // shadow A: eL  (row values; g=31 shifts by 2, rows 126/127 masked)
    float f0 = sh2 ? B.x : A.x;
    float f1 = sh2 ? B.y : A.y;
    float f2 = B.x, f3 = B.y;
    float eL0 = __expf(f0) * rm0;
    float eL1 = __expf(f1) * rm1;
    float eL2 = __expf(f2) * rm2;
    float eL3 = __expf(f3) * rm3;
    // shadow B: P from READ data  (P = exponent(max a) + 6; uniform/block)
    unsigned m01 = pkmax(u0.x, u0.y), m23 = pkmax(u0.z, u0.w);
    unsigned m45 = pkmax(u1.x, u1.y), m67 = pkmax(u1.z, u1.w);
    unsigned mC  = pkmax(pkmax(m01, m23), pkmax(m45, m67));
    h2 mh = bits_h2(mC);
    float fm = fmaxf((float)mh[0], (float)mh[1]);
    float gm = wave_max64(fm);
    int   P  = ((__float_as_int(gm) >> 23) & 0xFF) - 127 + 6;
    // dots: 4 rows x (2 chains of 4)
    float s0a = 0.f, s0b = 0.f, s1a = 0.f, s1b = 0.f;
    float s2a = 0.f, s2b = 0.f, s3a = 0.f, s3b = 0.f;
    s0a = dot2f(d0, E[0][0], s0a); s0a = dot2f(d1, E[0][1], s0a);
    s0a = dot2f(d2, E[0][2], s0a); s0a = dot2f(d3, E[0][3], s0a);
    s0b = dot2f(d4, E[0][4], s0b); s0b = dot2f(d5, E[0][5], s0b);
    s0b = dot2f(d6, E[0][6], s0b); s0b = dot2f(d7, E[0][7], s0b);
    s1a = dot2f(d0, E[1][0], s1a); s1a = dot2f(d1, E[1][1], s1a);
    s1a = dot2f(d2, E[1][2], s1a); s1a = dot2f(d3, E[1][3], s1a);
    s1b = dot2f(d4, E[1][4], s1b); s1b = dot2f(d5, E[1][5], s1b);
    s1b = dot2f(d6, E[1][6], s1b); s1b = dot2f(d7, E[1][7], s1b);
    s2a = dot2f(d0, E[2][0], s2a); s2a = dot2f(d1, E[2][1], s2a);
    s2a = dot2f(d2, E[2][2], s2a); s2a = dot2f(d3, E[2][3], s2a);
    s2b = dot2f(d4, E[2][4], s2b); s2b = dot2f(d5, E[2][5], s2b);
    s2b = dot2f(d6, E[2][6], s2b); s2b = dot2f(d7, E[2][7], s2b);
    s3a = dot2f(d0, E[3][0], s3a); s3a = dot2f(d1, E[3][1], s3a);
    s3a = dot2f(d2, E[3][2], s3a); s3a = dot2f(d3, E[3][3], s3a);
    s3b = dot2f(d4, E[3][4], s3b); s3b = dot2f(d5, E[3][5], s3b);
    s3b = dot2f(d6, E[3][6], s3b); s3b = dot2f(d7, E[3][7], s3b);
    // reduce over the 8 lanes/row (pure VALU butterfly)
    float s0 = colsum8(s0a + s0b);
    float s1 = colsum8(s1a + s1b);
    float s2 = colsum8(s2a + s2b);
    float s3 = colsum8(s3a + s3b);
    // tail
    float w0 = s0 * eL0, w1 = s1 * eL1, w2 = s2 * eL2, w3 = s3 * eL3;
    float sc = __int_as_float((127 - P) << 23);   // 2^-P, EXACT
    h2 pk0, pk1;
    pk0[0] = (half_t)(w0 * sc);  pk0[1] = (half_t)(w1 * sc);
    pk1[0] = (half_t)(w2 * sc);  pk1[1] = (half_t)(w3 * sc);
    if (writer) {
      uint2 pk2; pk2.x = h2_bits(pk0); pk2.y = h2_bits(pk1);
      *(uint2*)(&a_sh[par ^ 1][2 * g]) = pk2;     // ds_write_b64, byte 8g
    }
    Kout = Kacc;  Kacc += P;                      // exact side chain
    asm volatile("s_waitcnt lgkmcnt(0)\n\ts_barrier" ::: "memory");
    w0_out = w0; w1_out = w1; w2_out = w2; w3_out = w3;
    par ^= 1;
  };

  int t = 0;
  for (; t + 4 <= len; t += 4) {
    int q0 = t + 4, q1 = t + 5, q2 = t + 6, q3 = t + 7;
    q0 = (q0 < TB) ? q0 : (TB - 1);  q1 = (q1 < TB) ? q1 : (TB - 1);
    q2 = (q2 < TB) ? q2 : (TB - 1);  q3 = (q3 < TB) ? q3 : (TB - 1);
    step(pA[0], pB[0]);
    pA[0] = *(const float2*)(lgbase + (size_t)q0 * NUM + clb);
    pB[0] = *(const float2*)(lgbase + (size_t)q0 * NUM + clb + 2);
    step(pA[1], pB[1]);
    pA[1] = *(const float2*)(lgbase + (size_t)q1 * NUM + clb);
    pB[1] = *(const float2*)(lgbase + (size_t)q1 * NUM + clb + 2);
    step(pA[2], pB[2]);
    pA[2] = *(const float2*)(lgbase + (size_t)q2 * NUM + clb);
    pB[2] = *(const float2*)(lgbase + (size_t)q2 * NUM + clb + 2);
    step(pA[3], pB[3]);
    pA[3] = *(const float2*)(lgbase + (size_t)q3 * NUM + clb);
    pB[3] = *(const float2*)(lgbase + (size_t)q3 * NUM + clb + 2);
  }
  const int rem = len - t;
  if (rem > 0) step(pA[0], pB[0]);
  if (rem > 1) step(pA[1], pB[1]);
  if (rem > 2) step(pA[2], pB[2]);

  // ---- alpha_len[r] = Kout*ln2 + log(w_len[r]); norm = logsumexp(+trans_end)
  const float LN2 = 0.6931471805599453f;
  float K = (float)Kout * LN2;
  float vv0 = K + __logf(w0_out) + trans[(LBL - 1) * LBL + row0 + 0];
  float vv1 = K + __logf(w1_out) + trans[(LBL - 1) * LBL + row0 + 1];
  float vv2 = K + __logf(w2_out) + trans[(LBL - 1) * LBL + row0 + 2];
  float vv3 = K + __logf(w3_out) + trans[(LBL - 1) * LBL + row0 + 3];
  if (!writer) {                                   // dedupe the 8 replicas
    vv0 = vv1 = vv2 = vv3 = -__builtin_inff();
  }
  float vm = fmaxf(fmaxf(vv0, vv1), fmaxf(vv2, vv3));
  float M = wave_max64(vm);
  float p = __expf(vv0 - M) + __expf(vv1 - M) + __expf(vv2 - M) + __expf(vv3 - M);
  #pragma unroll
  for (int o = 1; o < 64; o <<= 1) p += __shfl_xor(p, o);
  if (l == 0) { Msh[wid] = M; psh[wid] = p; }
  __syncthreads();
  if (tid == 0) {
    float gT = goldsh[0] + goldsh[1] + goldsh[2] + goldsh[3];
    float Mg = fmaxf(fmaxf(Msh[0], Msh[1]), fmaxf(Msh[2], Msh[3]));
    float pg = psh[0] * __expf(Msh[0] - Mg) + psh[1] * __expf(Msh[1] - Mg)
             + psh[2] * __expf(Msh[2] - Mg) + psh[3] * __expf(Msh[3] - Mg);
    out[b] = gT - (Mg + __logf(pg));
  }
}

extern "C" void kernel_launch(void* const* d_in, const int* in_sizes, int n_in,
                              void* d_out, int out_size, void* d_ws, size_t ws_size,
                              hipStream_t stream) {
  const float* logits = (const float*)d_in[0];
  const int*   labels = (const int*)d_in[1];
  const int*   lens   = (const int*)d_in[2];
  const float* trans  = (const float*)d_in[3];
  float* out = (float*)d_out;
  (void)in_sizes; (void)n_in; (void)out_size; (void)d_ws; (void)ws_size;
  crf_fwd<<<256, 256, 0, stream>>>(logits, labels, lens, trans, out);
}